// Round 14
// baseline (393.996 us; speedup 1.0000x reference)
//
#include <hip/hip_runtime.h>
#include <hip/hip_bf16.h>

// GraphAttentionLayer: B=8,N=1024,FIN=E=OUT=128,NH=8,HD=16. f32 in/out.
// R14: (1) flash LDS 41728->39680B (Vs stride 144, head h at h*18) =>
// 4 blocks/CU (__launch_bounds__(256,4)); inner loop unchanged from R13.
// (2) Hp GEMM -> MFMA (Hb bf16 cast + WlinTb in prep). (3) qkv + z-gate
// merged into one 704-block dispatch. 5 dispatches total.

using u16 = unsigned short;
typedef short bf16x8 __attribute__((ext_vector_type(8)));
typedef float f32x4 __attribute__((ext_vector_type(4)));
typedef _Float16 f16;
typedef _Float16 f16x2 __attribute__((ext_vector_type(2)));

#if defined(__has_builtin)
#if __has_builtin(__builtin_amdgcn_fdot2)
#define HAS_FDOT2 1
#endif
#endif

__device__ __forceinline__ u16 f2b(float f) {
    unsigned u = __float_as_uint(f);
    return (u16)((u + 0x7fffu + ((u >> 16) & 1u)) >> 16);  // RNE
}

// ---- prep: Hb bf16 cast + rowsum zero + WlinTb/WinTb bf16 + Wcomb ----
__global__ void prep_k(const float* __restrict__ H, const float* __restrict__ Wlin,
                       const float* __restrict__ Win,
                       const float* __restrict__ Wout, const float* __restrict__ Wfin,
                       const float* __restrict__ bout, const float* __restrict__ bfin,
                       u16* __restrict__ Hb, u16* __restrict__ WlinTb,
                       u16* __restrict__ WinTb,
                       float* __restrict__ WcombT, float* __restrict__ bcomb,
                       float* __restrict__ rowsum) {
    int i = blockIdx.x * 256 + threadIdx.x;   // 0..1130495
    if (i < 1048576) {
        Hb[i] = f2b(H[i]);
        return;
    }
    int j = i - 1048576;                      // 0..81919
    if (j < 8192) rowsum[j] = 0.f;
    if (j < 16384) {
        WlinTb[(j & 127) * 128 + (j >> 7)] = f2b(Wlin[j]);
    } else if (j < 65536) {
        int k = j - 16384;                    // Win 128x384 -> WinTb 384x128 bf16
        int r = k / 384, c = k - r * 384;
        WinTb[c * 128 + r] = f2b(Win[k]);
    } else {
        int k = j - 65536;
        int o = k & 127, e = k >> 7;          // o fastest: Wfin coalesced
        float s = 0.f;
        for (int kk = 0; kk < 128; ++kk)
            s = fmaf(Wout[e * 128 + kk], Wfin[kk * 128 + o], s);
        WcombT[o * 128 + e] = s;
        if (e == 0) {
            float sb = bfin[o];
            for (int kk = 0; kk < 128; ++kk)
                sb = fmaf(bout[kk], Wfin[kk * 128 + o], sb);
            bcomb[o] = sb;
        }
    }
}

// ------- Hp = Hb @ WlinTb^T + blin : MFMA, 128-row blocks, bf16 out -------
__global__ __launch_bounds__(256)
void mfma_hp(const u16* __restrict__ Ab, const u16* __restrict__ Bb,
             const float* __restrict__ bias, u16* __restrict__ C) {
    const int m0 = blockIdx.x * 128;
    const int t = threadIdx.x;
    const int wave = t >> 6, lane = t & 63;
    const int wm = (wave >> 1) * 64, wn = (wave & 1) * 64;
    const int m16 = lane & 15, kq = lane >> 4;
    f32x4 acc[4][4] = {};

#pragma unroll
    for (int kc = 0; kc < 4; ++kc) {
        bf16x8 af[4], bf[4];
#pragma unroll
        for (int i = 0; i < 4; ++i)
            af[i] = *(const bf16x8*)&Ab[(long long)(m0 + wm + i * 16 + m16) * 128 + kc * 32 + kq * 8];
#pragma unroll
        for (int j = 0; j < 4; ++j)
            bf[j] = *(const bf16x8*)&Bb[(long long)(wn + j * 16 + m16) * 128 + kc * 32 + kq * 8];
#pragma unroll
        for (int i = 0; i < 4; ++i)
#pragma unroll
            for (int j = 0; j < 4; ++j)
                acc[i][j] = __builtin_amdgcn_mfma_f32_16x16x32_bf16(af[i], bf[j], acc[i][j], 0, 0, 0);
    }
#pragma unroll
    for (int i = 0; i < 4; ++i) {
#pragma unroll
        for (int r = 0; r < 4; ++r) {
            long long row = m0 + wm + i * 16 + kq * 4 + r;
#pragma unroll
            for (int j = 0; j < 4; ++j) {
                int col = wn + j * 16 + m16;
                C[row * 128 + col] = f2b(acc[i][j][r] + bias[col]);
            }
        }
    }
}

// ---- merged: blk<512 -> z = lrelu(Hpb@Hpb^T)*A + exp-rowsum;
//      blk>=512 -> qkv = Hpb @ WinTb^T + bin (mixed layout) ----
__global__ __launch_bounds__(256)
void mfma_qkvz(const u16* __restrict__ Hpb, const u16* __restrict__ WinTb,
               const float* __restrict__ bin, float* __restrict__ Cq,
               const float* __restrict__ G, float* __restrict__ Z,
               float* __restrict__ rowsum) {
    const int blk = blockIdx.x;
    const int t = threadIdx.x;
    const int wave = t >> 6, lane = t & 63;
    const int wm = (wave >> 1) * 64, wn = (wave & 1) * 64;
    const int m16 = lane & 15, kq = lane >> 4;
    f32x4 acc[4][4] = {};

    if (blk < 512) {
        const int b = blk >> 6, mt = (blk >> 3) & 7, nt = blk & 7;
        const u16* Ab = Hpb + (long long)b * 1024 * 128;
        const int m0 = mt * 128, n0 = nt * 128;
#pragma unroll
        for (int kc = 0; kc < 4; ++kc) {
            bf16x8 af[4], bf[4];
#pragma unroll
            for (int i = 0; i < 4; ++i)
                af[i] = *(const bf16x8*)&Ab[(long long)(m0 + wm + i * 16 + m16) * 128 + kc * 32 + kq * 8];
#pragma unroll
            for (int j = 0; j < 4; ++j)
                bf[j] = *(const bf16x8*)&Ab[(long long)(n0 + wn + j * 16 + m16) * 128 + kc * 32 + kq * 8];
#pragma unroll
            for (int i = 0; i < 4; ++i)
#pragma unroll
                for (int j = 0; j < 4; ++j)
                    acc[i][j] = __builtin_amdgcn_mfma_f32_16x16x32_bf16(af[i], bf[j], acc[i][j], 0, 0, 0);
        }
        const long long zb = (long long)b * 1024 * 1024;
#pragma unroll
        for (int i = 0; i < 4; ++i) {
#pragma unroll
            for (int r = 0; r < 4; ++r) {
                int row = m0 + wm + i * 16 + kq * 4 + r;
                float es = 0.f;
#pragma unroll
                for (int j = 0; j < 4; ++j) {
                    int col = n0 + wn + j * 16 + m16;
                    float v = acc[i][j][r];
                    v = v >= 0.f ? v : 0.2f * v;                  // LeakyReLU(0.2)
                    v *= G[zb + (long long)row * 1024 + col];     // * adjacency gate
                    Z[zb + (long long)row * 1024 + col] = v;
                    es += __expf(v);                              // m=0: |z| bounded
                }
#pragma unroll
                for (int off = 1; off < 16; off <<= 1) es += __shfl_xor(es, off);
                if (m16 == 0) atomicAdd(&rowsum[b * 1024 + row], es);
            }
        }
    } else {
        const int q = blk - 512;
        const int mt = q & 63, slab = q >> 6;   // 0=q, 1=k, 2=v
        const int m0 = mt * 128;
        const u16* Bslab = WinTb + (long long)slab * 128 * 128;
#pragma unroll
        for (int kc = 0; kc < 4; ++kc) {
            bf16x8 af[4], bf[4];
#pragma unroll
            for (int i = 0; i < 4; ++i)
                af[i] = *(const bf16x8*)&Hpb[(long long)(m0 + wm + i * 16 + m16) * 128 + kc * 32 + kq * 8];
#pragma unroll
            for (int j = 0; j < 4; ++j)
                bf[j] = *(const bf16x8*)&Bslab[(long long)(wn + j * 16 + m16) * 128 + kc * 32 + kq * 8];
#pragma unroll
            for (int i = 0; i < 4; ++i)
#pragma unroll
                for (int j = 0; j < 4; ++j)
                    acc[i][j] = __builtin_amdgcn_mfma_f32_16x16x32_bf16(af[i], bf[j], acc[i][j], 0, 0, 0);
        }
        f16* Ck = (f16*)Cq;
#pragma unroll
        for (int i = 0; i < 4; ++i) {
#pragma unroll
            for (int r = 0; r < 4; ++r) {
                long long row = m0 + wm + i * 16 + kq * 4 + r;
#pragma unroll
                for (int j = 0; j < 4; ++j) {
                    int col = wn + j * 16 + m16;
                    float v = acc[i][j][r] + bin[slab * 128 + col];
                    if (slab == 0)      Cq[row * 320 + col] = v;
                    else if (slab == 1) Ck[row * 640 + 256 + col] = (f16)v;
                    else                Cq[row * 320 + 192 + col] = v;
                }
            }
        }
    }
}

// ---- flash pass 1: f16 K dot2, 2 rows/thread, 64-row blocks, 4 blk/CU ----
// grid (16,8,8) = 1024 blocks; LDS 39680B => 4 blocks/CU (4 waves/SIMD).
__global__ __launch_bounds__(256, 4)
void flash_pass1(const float* __restrict__ qkv, float* __restrict__ zaw,
                 const float* __restrict__ rowsum, float* __restrict__ lbuf) {
    const int b = blockIdx.y;
    const int n0 = blockIdx.x * 64;
    const int c = blockIdx.z;
    const int t = threadIdx.x;
    const int rg = t >> 3;    // 0..31 slots (2 rows each)
    const int h = t & 7;      // head

    __shared__ u16   Ks[32 * 200];   // f16, head h at col h*24 (all 32 banks)
    __shared__ float Vs[32 * 144];   // f32, head h at col h*18
    __shared__ float AWs[32 * 66];   // transposed [mm][qrow 0..63], stride 66

    const int qr = t >> 2;           // AW staging row (0..63)
    const int mmc = (t & 3) * 8;     // AW staging col group
    const float inv0 = 1.f / rowsum[b * 1024 + n0 + qr];

    f16x2 q2[2][8];
    float acc[2][16];
    float l[2] = {0.f, 0.f};
#pragma unroll
    for (int r = 0; r < 2; ++r) {
        const float* qrow = qkv + (long long)(b * 1024 + n0 + rg * 2 + r) * 320 + h * 16;
#pragma unroll
        for (int j = 0; j < 4; ++j) {
            float4 u = *(const float4*)&qrow[j * 4];
            q2[r][j * 2 + 0] = f16x2{(f16)(u.x * 0.25f), (f16)(u.y * 0.25f)};
            q2[r][j * 2 + 1] = f16x2{(f16)(u.z * 0.25f), (f16)(u.w * 0.25f)};
        }
#pragma unroll
        for (int d = 0; d < 16; ++d) acc[r][d] = 0.f;
    }

    for (int tile = 0; tile < 4; ++tile) {
        const int kbase = c * 128 + tile * 32;
        __syncthreads();
        {
            const int row = t >> 3, hh = t & 7;
            const long long grow = b * 1024 + kbase + row;
            const uint4* ksrc = (const uint4*)((const char*)qkv + grow * 1280 + 512 + hh * 32);
            *(uint4*)&Ks[row * 200 + hh * 24] = ksrc[0];
            *(uint4*)&Ks[row * 200 + hh * 24 + 8] = ksrc[1];
            const float* vsrc = qkv + grow * 320 + 192 + hh * 16;
#pragma unroll
            for (int j = 0; j < 4; ++j)
                *(float4*)&Vs[row * 144 + hh * 18 + j * 4] = *(const float4*)&vsrc[j * 4];
        }
        {
            const float* zrow = zaw + ((long long)(b * 1024 + n0 + qr)) * 1024 + kbase + mmc;
#pragma unroll
            for (int jj = 0; jj < 2; ++jj) {
                float4 u = *(const float4*)&zrow[jj * 4];
                AWs[(mmc + jj * 4 + 0) * 66 + qr] = __expf(u.x) * inv0;
                AWs[(mmc + jj * 4 + 1) * 66 + qr] = __expf(u.y) * inv0;
                AWs[(mmc + jj * 4 + 2) * 66 + qr] = __expf(u.z) * inv0;
                AWs[(mmc + jj * 4 + 3) * 66 + qr] = __expf(u.w) * inv0;
            }
        }
        __syncthreads();

#pragma unroll 2
        for (int mm = 0; mm < 32; ++mm) {
            const f16x2* kp = (const f16x2*)&Ks[mm * 200 + h * 24];
            f16x2 k2[8];
#pragma unroll
            for (int d = 0; d < 8; ++d) k2[d] = kp[d];
            const float* vp = &Vs[mm * 144 + h * 18];
            float4 v0 = *(const float4*)&vp[0],  v1 = *(const float4*)&vp[4];
            float4 v2 = *(const float4*)&vp[8],  v3 = *(const float4*)&vp[12];
            float2 awv = *(const float2*)&AWs[mm * 66 + rg * 2];
            float aws[2] = {awv.x, awv.y};
#ifndef HAS_FDOT2
            float kf[16];
#pragma unroll
            for (int d = 0; d < 8; ++d) {
                kf[d * 2 + 0] = (float)k2[d].x;
                kf[d * 2 + 1] = (float)k2[d].y;
            }
#endif
#pragma unroll
            for (int r = 0; r < 2; ++r) {
                float s = aws[r];
#ifdef HAS_FDOT2
#pragma unroll
                for (int d = 0; d < 8; ++d)
                    s = __builtin_amdgcn_fdot2(q2[r][d], k2[d], s, false);
#else
#pragma unroll
                for (int d = 0; d < 8; ++d) {
                    s = fmaf((float)q2[r][d].x, kf[d * 2 + 0], s);
                    s = fmaf((float)q2[r][d].y, kf[d * 2 + 1], s);
                }
#endif
                float p = __expf(s);          // s in [-1,2]: safe, m=0
                l[r] += p;
                acc[r][0]  = fmaf(p, v0.x, acc[r][0]);
                acc[r][1]  = fmaf(p, v0.y, acc[r][1]);
                acc[r][2]  = fmaf(p, v0.z, acc[r][2]);
                acc[r][3]  = fmaf(p, v0.w, acc[r][3]);
                acc[r][4]  = fmaf(p, v1.x, acc[r][4]);
                acc[r][5]  = fmaf(p, v1.y, acc[r][5]);
                acc[r][6]  = fmaf(p, v1.z, acc[r][6]);
                acc[r][7]  = fmaf(p, v1.w, acc[r][7]);
                acc[r][8]  = fmaf(p, v2.x, acc[r][8]);
                acc[r][9]  = fmaf(p, v2.y, acc[r][9]);
                acc[r][10] = fmaf(p, v2.z, acc[r][10]);
                acc[r][11] = fmaf(p, v2.w, acc[r][11]);
                acc[r][12] = fmaf(p, v3.x, acc[r][12]);
                acc[r][13] = fmaf(p, v3.y, acc[r][13]);
                acc[r][14] = fmaf(p, v3.z, acc[r][14]);
                acc[r][15] = fmaf(p, v3.w, acc[r][15]);
            }
        }
    }
#pragma unroll
    for (int r = 0; r < 2; ++r) {
        const int grow = b * 1024 + n0 + rg * 2 + r;
        float* base = zaw + (long long)grow * 1024 + c * 128 + h * 16;
#pragma unroll
        for (int j = 0; j < 4; ++j) {
            float4 u;
            u.x = acc[r][j * 4 + 0]; u.y = acc[r][j * 4 + 1];
            u.z = acc[r][j * 4 + 2]; u.w = acc[r][j * 4 + 3];
            *(float4*)&base[j * 4] = u;
        }
        lbuf[((long long)grow * 8 + h) * 8 + c] = l[r];
    }
}

// -------- out = combine(partials) @ WcombT^T + bcomb, fused 64x64 --------
__global__ __launch_bounds__(256)
void out_fused(const float* __restrict__ zp, const float* __restrict__ lbuf,
               const float* __restrict__ Bm, const float* __restrict__ bias,
               float* __restrict__ C) {
    const int m0 = blockIdx.x * 64, n0 = blockIdx.y * 64;
    __shared__ float As[64][132];
    __shared__ float Bs[64][68];
    const int t = threadIdx.x;
    const int tx = t & 15, ty = t >> 4;

#pragma unroll
    for (int g = 0; g < 8; ++g) {
        int flat = g * 256 + t;
        int row = flat >> 5;
        int f4c = flat & 31;
        int d0 = f4c * 4, h = d0 >> 4;
        long long grow = m0 + row;
        const float* pb = zp + grow * 1024 + d0;
        float4 s = {0.f, 0.f, 0.f, 0.f};
#pragma unroll
        for (int c = 0; c < 8; ++c) {
            float4 a = *(const float4*)&pb[c * 128];
            s.x += a.x; s.y += a.y; s.z += a.z; s.w += a.w;
        }
        const float* lr = lbuf + (grow * 8 + h) * 8;
        float4 l0 = *(const float4*)&lr[0];
        float4 l1 = *(const float4*)&lr[4];
        float L = (l0.x + l0.y + l0.z + l0.w) + (l1.x + l1.y + l1.z + l1.w);
        float inv = 1.f / L;
        s.x *= inv; s.y *= inv; s.z *= inv; s.w *= inv;
        *(float4*)&As[row][d0] = s;
    }

    float acc[4][4] = {};
    for (int kt = 0; kt < 128; kt += 64) {
        __syncthreads();
#pragma unroll
        for (int r = 0; r < 4; ++r) {
            int flat = r * 256 + t;
            int row = flat >> 4;
            int k0 = (flat & 15) * 4;
            *(float4*)&Bs[row][k0] = *(const float4*)&Bm[(long long)(n0 + row) * 128 + kt + k0];
        }
        __syncthreads();
#pragma unroll
        for (int kc = 0; kc < 16; ++kc) {
            float4 a4[4], b4[4];
#pragma unroll
            for (int i = 0; i < 4; ++i) a4[i] = *(float4*)&As[16 * i + ty][kt + kc * 4];
#pragma unroll
            for (int j = 0; j < 4; ++j) b4[j] = *(float4*)&Bs[16 * j + tx][kc * 4];
#pragma unroll
            for (int i = 0; i < 4; ++i)
#pragma unroll
                for (int j = 0; j < 4; ++j) {
                    float s = acc[i][j];
                    s = fmaf(a4[i].x, b4[j].x, s);
                    s = fmaf(a4[i].y, b4[j].y, s);
                    s = fmaf(a4[i].z, b4[j].z, s);
                    s = fmaf(a4[i].w, b4[j].w, s);
                    acc[i][j] = s;
                }
        }
    }
#pragma unroll
    for (int i = 0; i < 4; ++i) {
        int row = m0 + 16 * i + ty;
#pragma unroll
        for (int j = 0; j < 4; ++j) {
            int col = n0 + 16 * j + tx;
            C[(long long)row * 128 + col] = acc[i][j] + bias[col];
        }
    }
}

extern "C" void kernel_launch(void* const* d_in, const int* in_sizes, int n_in,
                              void* d_out, int out_size, void* d_ws, size_t ws_size,
                              hipStream_t stream) {
    (void)in_sizes; (void)n_in; (void)out_size; (void)ws_size;
    const float* H    = (const float*)d_in[0];
    const float* Aadj = (const float*)d_in[1];
    const float* Wlin = (const float*)d_in[2];
    const float* blin = (const float*)d_in[3];
    const float* Win  = (const float*)d_in[4];
    const float* bin  = (const float*)d_in[5];
    const float* Wout = (const float*)d_in[6];
    const float* bout = (const float*)d_in[7];
    const float* Wfin = (const float*)d_in[8];
    const float* bfin = (const float*)d_in[9];
    float* out = (float*)d_out;
    char* ws = (char*)d_ws;

    u16*   WlinTb = (u16*)(ws + 0);           // 32 KB bf16
    u16*   WinTb  = (u16*)(ws + 32768);       // 96 KB bf16
    float* WcombT = (float*)(ws + 131072);    // 64 KB
    float* bcomb  = (float*)(ws + 196608);    // 512 B
    float* rowsum = (float*)(ws + 197120);    // 32 KB
    u16*   Hb     = (u16*)(ws + 262144);      // 2 MB bf16 (H cast)
    u16*   Hpb    = (u16*)(ws + 2359296);     // 2 MB bf16
    float* qkv    = (float*)(ws + 4653056);   // 10.5 MB mixed (q f32|k f16|v f32)
    float* lbuf   = (float*)(ws + 17235968);  // 2 MB
    float* z      = (float*)(ws + 19333120);  // 32 MB (scores -> partials)

    // prep: Hb cast (1M) + weights (81920) => 4416 blocks
    prep_k<<<4416, 256, 0, stream>>>(H, Wlin, Win, Wout, Wfin, bout, bfin,
                                     Hb, WlinTb, WinTb, WcombT, bcomb, rowsum);
    // Hp = Hb @ WlinTb^T + blin -> bf16  (MFMA)
    mfma_hp<<<64, 256, 0, stream>>>(Hb, WlinTb, blin, Hpb);
    // merged: z-gate (512 blocks) + qkv (192 blocks)
    mfma_qkvz<<<704, 256, 0, stream>>>(Hpb, WinTb, bin, qkv, Aadj, z, rowsum);
    // flash pass 1 (f16 dot2; aw inline; partials into z + lbuf)
    flash_pass1<<<dim3(16, 8, 8), 256, 0, stream>>>(qkv, z, rowsum, lbuf);
    // out = combine(partials) @ Wcomb + bcomb
    out_fused<<<dim3(128, 2), 256, 0, stream>>>(z, lbuf, WcombT, bcomb, out);
}

// Round 15
// 390.001 us; speedup vs baseline: 1.0102x; 1.0102x over previous
//
#include <hip/hip_runtime.h>
#include <hip/hip_bf16.h>

// GraphAttentionLayer: B=8,N=1024,FIN=E=OUT=128,NH=8,HD=16. f32 in/out.
// R15: revert R14's __launch_bounds__(256,4) on flash -- it capped VGPRs at
// 64 (natural pressure 68) and spilled the inner loop to scratch (258us,
// VALUBusy 14%). Back to (256,3): 68 VGPR, no spill, 3 blocks/CU.
// Keeps R14's wins: MFMA Hp, merged qkv+z dispatch, Hb bf16 cast in prep,
// Vs stride 144 (write conflicts 8->4-way, reads free).

using u16 = unsigned short;
typedef short bf16x8 __attribute__((ext_vector_type(8)));
typedef float f32x4 __attribute__((ext_vector_type(4)));
typedef _Float16 f16;
typedef _Float16 f16x2 __attribute__((ext_vector_type(2)));

#if defined(__has_builtin)
#if __has_builtin(__builtin_amdgcn_fdot2)
#define HAS_FDOT2 1
#endif
#endif

__device__ __forceinline__ u16 f2b(float f) {
    unsigned u = __float_as_uint(f);
    return (u16)((u + 0x7fffu + ((u >> 16) & 1u)) >> 16);  // RNE
}

// ---- prep: Hb bf16 cast + rowsum zero + WlinTb/WinTb bf16 + Wcomb ----
__global__ void prep_k(const float* __restrict__ H, const float* __restrict__ Wlin,
                       const float* __restrict__ Win,
                       const float* __restrict__ Wout, const float* __restrict__ Wfin,
                       const float* __restrict__ bout, const float* __restrict__ bfin,
                       u16* __restrict__ Hb, u16* __restrict__ WlinTb,
                       u16* __restrict__ WinTb,
                       float* __restrict__ WcombT, float* __restrict__ bcomb,
                       float* __restrict__ rowsum) {
    int i = blockIdx.x * 256 + threadIdx.x;   // 0..1130495
    if (i < 1048576) {
        Hb[i] = f2b(H[i]);
        return;
    }
    int j = i - 1048576;                      // 0..81919
    if (j < 8192) rowsum[j] = 0.f;
    if (j < 16384) {
        WlinTb[(j & 127) * 128 + (j >> 7)] = f2b(Wlin[j]);
    } else if (j < 65536) {
        int k = j - 16384;                    // Win 128x384 -> WinTb 384x128 bf16
        int r = k / 384, c = k - r * 384;
        WinTb[c * 128 + r] = f2b(Win[k]);
    } else {
        int k = j - 65536;
        int o = k & 127, e = k >> 7;          // o fastest: Wfin coalesced
        float s = 0.f;
        for (int kk = 0; kk < 128; ++kk)
            s = fmaf(Wout[e * 128 + kk], Wfin[kk * 128 + o], s);
        WcombT[o * 128 + e] = s;
        if (e == 0) {
            float sb = bfin[o];
            for (int kk = 0; kk < 128; ++kk)
                sb = fmaf(bout[kk], Wfin[kk * 128 + o], sb);
            bcomb[o] = sb;
        }
    }
}

// ------- Hp = Hb @ WlinTb^T + blin : MFMA, 128-row blocks, bf16 out -------
__global__ __launch_bounds__(256)
void mfma_hp(const u16* __restrict__ Ab, const u16* __restrict__ Bb,
             const float* __restrict__ bias, u16* __restrict__ C) {
    const int m0 = blockIdx.x * 128;
    const int t = threadIdx.x;
    const int wave = t >> 6, lane = t & 63;
    const int wm = (wave >> 1) * 64, wn = (wave & 1) * 64;
    const int m16 = lane & 15, kq = lane >> 4;
    f32x4 acc[4][4] = {};

#pragma unroll
    for (int kc = 0; kc < 4; ++kc) {
        bf16x8 af[4], bf[4];
#pragma unroll
        for (int i = 0; i < 4; ++i)
            af[i] = *(const bf16x8*)&Ab[(long long)(m0 + wm + i * 16 + m16) * 128 + kc * 32 + kq * 8];
#pragma unroll
        for (int j = 0; j < 4; ++j)
            bf[j] = *(const bf16x8*)&Bb[(long long)(wn + j * 16 + m16) * 128 + kc * 32 + kq * 8];
#pragma unroll
        for (int i = 0; i < 4; ++i)
#pragma unroll
            for (int j = 0; j < 4; ++j)
                acc[i][j] = __builtin_amdgcn_mfma_f32_16x16x32_bf16(af[i], bf[j], acc[i][j], 0, 0, 0);
    }
#pragma unroll
    for (int i = 0; i < 4; ++i) {
#pragma unroll
        for (int r = 0; r < 4; ++r) {
            long long row = m0 + wm + i * 16 + kq * 4 + r;
#pragma unroll
            for (int j = 0; j < 4; ++j) {
                int col = wn + j * 16 + m16;
                C[row * 128 + col] = f2b(acc[i][j][r] + bias[col]);
            }
        }
    }
}

// ---- merged: blk<512 -> z = lrelu(Hpb@Hpb^T)*A + exp-rowsum;
//      blk>=512 -> qkv = Hpb @ WinTb^T + bin (mixed layout) ----
__global__ __launch_bounds__(256)
void mfma_qkvz(const u16* __restrict__ Hpb, const u16* __restrict__ WinTb,
               const float* __restrict__ bin, float* __restrict__ Cq,
               const float* __restrict__ G, float* __restrict__ Z,
               float* __restrict__ rowsum) {
    const int blk = blockIdx.x;
    const int t = threadIdx.x;
    const int wave = t >> 6, lane = t & 63;
    const int wm = (wave >> 1) * 64, wn = (wave & 1) * 64;
    const int m16 = lane & 15, kq = lane >> 4;
    f32x4 acc[4][4] = {};

    if (blk < 512) {
        const int b = blk >> 6, mt = (blk >> 3) & 7, nt = blk & 7;
        const u16* Ab = Hpb + (long long)b * 1024 * 128;
        const int m0 = mt * 128, n0 = nt * 128;
#pragma unroll
        for (int kc = 0; kc < 4; ++kc) {
            bf16x8 af[4], bf[4];
#pragma unroll
            for (int i = 0; i < 4; ++i)
                af[i] = *(const bf16x8*)&Ab[(long long)(m0 + wm + i * 16 + m16) * 128 + kc * 32 + kq * 8];
#pragma unroll
            for (int j = 0; j < 4; ++j)
                bf[j] = *(const bf16x8*)&Ab[(long long)(n0 + wn + j * 16 + m16) * 128 + kc * 32 + kq * 8];
#pragma unroll
            for (int i = 0; i < 4; ++i)
#pragma unroll
                for (int j = 0; j < 4; ++j)
                    acc[i][j] = __builtin_amdgcn_mfma_f32_16x16x32_bf16(af[i], bf[j], acc[i][j], 0, 0, 0);
        }
        const long long zb = (long long)b * 1024 * 1024;
#pragma unroll
        for (int i = 0; i < 4; ++i) {
#pragma unroll
            for (int r = 0; r < 4; ++r) {
                int row = m0 + wm + i * 16 + kq * 4 + r;
                float es = 0.f;
#pragma unroll
                for (int j = 0; j < 4; ++j) {
                    int col = n0 + wn + j * 16 + m16;
                    float v = acc[i][j][r];
                    v = v >= 0.f ? v : 0.2f * v;                  // LeakyReLU(0.2)
                    v *= G[zb + (long long)row * 1024 + col];     // * adjacency gate
                    Z[zb + (long long)row * 1024 + col] = v;
                    es += __expf(v);                              // m=0: |z| bounded
                }
#pragma unroll
                for (int off = 1; off < 16; off <<= 1) es += __shfl_xor(es, off);
                if (m16 == 0) atomicAdd(&rowsum[b * 1024 + row], es);
            }
        }
    } else {
        const int q = blk - 512;
        const int mt = q & 63, slab = q >> 6;   // 0=q, 1=k, 2=v
        const int m0 = mt * 128;
        const u16* Bslab = WinTb + (long long)slab * 128 * 128;
#pragma unroll
        for (int kc = 0; kc < 4; ++kc) {
            bf16x8 af[4], bf[4];
#pragma unroll
            for (int i = 0; i < 4; ++i)
                af[i] = *(const bf16x8*)&Hpb[(long long)(m0 + wm + i * 16 + m16) * 128 + kc * 32 + kq * 8];
#pragma unroll
            for (int j = 0; j < 4; ++j)
                bf[j] = *(const bf16x8*)&Bslab[(long long)(wn + j * 16 + m16) * 128 + kc * 32 + kq * 8];
#pragma unroll
            for (int i = 0; i < 4; ++i)
#pragma unroll
                for (int j = 0; j < 4; ++j)
                    acc[i][j] = __builtin_amdgcn_mfma_f32_16x16x32_bf16(af[i], bf[j], acc[i][j], 0, 0, 0);
        }
        f16* Ck = (f16*)Cq;
#pragma unroll
        for (int i = 0; i < 4; ++i) {
#pragma unroll
            for (int r = 0; r < 4; ++r) {
                long long row = m0 + wm + i * 16 + kq * 4 + r;
#pragma unroll
                for (int j = 0; j < 4; ++j) {
                    int col = wn + j * 16 + m16;
                    float v = acc[i][j][r] + bin[slab * 128 + col];
                    if (slab == 0)      Cq[row * 320 + col] = v;
                    else if (slab == 1) Ck[row * 640 + 256 + col] = (f16)v;
                    else                Cq[row * 320 + 192 + col] = v;
                }
            }
        }
    }
}

// ---- flash pass 1: f16 K dot2, 2 rows/thread, 64-row blocks ----
// grid (16,8,8) = 1024 blocks; VGPR ~68 -> 3 blocks/CU. LDS 39.9KB.
// NOTE: do NOT raise min-waves to 4 -- caps VGPR at 64 and spills (R14).
__global__ __launch_bounds__(256, 3)
void flash_pass1(const float* __restrict__ qkv, float* __restrict__ zaw,
                 const float* __restrict__ rowsum, float* __restrict__ lbuf) {
    const int b = blockIdx.y;
    const int n0 = blockIdx.x * 64;
    const int c = blockIdx.z;
    const int t = threadIdx.x;
    const int rg = t >> 3;    // 0..31 slots (2 rows each)
    const int h = t & 7;      // head

    __shared__ u16   Ks[32 * 200];   // f16, head h at col h*24
    __shared__ float Vs[32 * 144];   // f32, head h at col h*18
    __shared__ float AWs[32 * 66];   // transposed [mm][qrow 0..63], stride 66

    const int qr = t >> 2;           // AW staging row (0..63)
    const int mmc = (t & 3) * 8;     // AW staging col group
    const float inv0 = 1.f / rowsum[b * 1024 + n0 + qr];

    f16x2 q2[2][8];
    float acc[2][16];
    float l[2] = {0.f, 0.f};
#pragma unroll
    for (int r = 0; r < 2; ++r) {
        const float* qrow = qkv + (long long)(b * 1024 + n0 + rg * 2 + r) * 320 + h * 16;
#pragma unroll
        for (int j = 0; j < 4; ++j) {
            float4 u = *(const float4*)&qrow[j * 4];
            q2[r][j * 2 + 0] = f16x2{(f16)(u.x * 0.25f), (f16)(u.y * 0.25f)};
            q2[r][j * 2 + 1] = f16x2{(f16)(u.z * 0.25f), (f16)(u.w * 0.25f)};
        }
#pragma unroll
        for (int d = 0; d < 16; ++d) acc[r][d] = 0.f;
    }

    for (int tile = 0; tile < 4; ++tile) {
        const int kbase = c * 128 + tile * 32;
        __syncthreads();
        {
            const int row = t >> 3, hh = t & 7;
            const long long grow = b * 1024 + kbase + row;
            const uint4* ksrc = (const uint4*)((const char*)qkv + grow * 1280 + 512 + hh * 32);
            *(uint4*)&Ks[row * 200 + hh * 24] = ksrc[0];
            *(uint4*)&Ks[row * 200 + hh * 24 + 8] = ksrc[1];
            const float* vsrc = qkv + grow * 320 + 192 + hh * 16;
#pragma unroll
            for (int j = 0; j < 4; ++j)
                *(float4*)&Vs[row * 144 + hh * 18 + j * 4] = *(const float4*)&vsrc[j * 4];
        }
        {
            const float* zrow = zaw + ((long long)(b * 1024 + n0 + qr)) * 1024 + kbase + mmc;
#pragma unroll
            for (int jj = 0; jj < 2; ++jj) {
                float4 u = *(const float4*)&zrow[jj * 4];
                AWs[(mmc + jj * 4 + 0) * 66 + qr] = __expf(u.x) * inv0;
                AWs[(mmc + jj * 4 + 1) * 66 + qr] = __expf(u.y) * inv0;
                AWs[(mmc + jj * 4 + 2) * 66 + qr] = __expf(u.z) * inv0;
                AWs[(mmc + jj * 4 + 3) * 66 + qr] = __expf(u.w) * inv0;
            }
        }
        __syncthreads();

#pragma unroll 2
        for (int mm = 0; mm < 32; ++mm) {
            const f16x2* kp = (const f16x2*)&Ks[mm * 200 + h * 24];
            f16x2 k2[8];
#pragma unroll
            for (int d = 0; d < 8; ++d) k2[d] = kp[d];
            const float* vp = &Vs[mm * 144 + h * 18];
            float4 v0 = *(const float4*)&vp[0],  v1 = *(const float4*)&vp[4];
            float4 v2 = *(const float4*)&vp[8],  v3 = *(const float4*)&vp[12];
            float2 awv = *(const float2*)&AWs[mm * 66 + rg * 2];
            float aws[2] = {awv.x, awv.y};
#ifndef HAS_FDOT2
            float kf[16];
#pragma unroll
            for (int d = 0; d < 8; ++d) {
                kf[d * 2 + 0] = (float)k2[d].x;
                kf[d * 2 + 1] = (float)k2[d].y;
            }
#endif
#pragma unroll
            for (int r = 0; r < 2; ++r) {
                float s = aws[r];
#ifdef HAS_FDOT2
#pragma unroll
                for (int d = 0; d < 8; ++d)
                    s = __builtin_amdgcn_fdot2(q2[r][d], k2[d], s, false);
#else
#pragma unroll
                for (int d = 0; d < 8; ++d) {
                    s = fmaf((float)q2[r][d].x, kf[d * 2 + 0], s);
                    s = fmaf((float)q2[r][d].y, kf[d * 2 + 1], s);
                }
#endif
                float p = __expf(s);          // s in [-1,2]: safe, m=0
                l[r] += p;
                acc[r][0]  = fmaf(p, v0.x, acc[r][0]);
                acc[r][1]  = fmaf(p, v0.y, acc[r][1]);
                acc[r][2]  = fmaf(p, v0.z, acc[r][2]);
                acc[r][3]  = fmaf(p, v0.w, acc[r][3]);
                acc[r][4]  = fmaf(p, v1.x, acc[r][4]);
                acc[r][5]  = fmaf(p, v1.y, acc[r][5]);
                acc[r][6]  = fmaf(p, v1.z, acc[r][6]);
                acc[r][7]  = fmaf(p, v1.w, acc[r][7]);
                acc[r][8]  = fmaf(p, v2.x, acc[r][8]);
                acc[r][9]  = fmaf(p, v2.y, acc[r][9]);
                acc[r][10] = fmaf(p, v2.z, acc[r][10]);
                acc[r][11] = fmaf(p, v2.w, acc[r][11]);
                acc[r][12] = fmaf(p, v3.x, acc[r][12]);
                acc[r][13] = fmaf(p, v3.y, acc[r][13]);
                acc[r][14] = fmaf(p, v3.z, acc[r][14]);
                acc[r][15] = fmaf(p, v3.w, acc[r][15]);
            }
        }
    }
#pragma unroll
    for (int r = 0; r < 2; ++r) {
        const int grow = b * 1024 + n0 + rg * 2 + r;
        float* base = zaw + (long long)grow * 1024 + c * 128 + h * 16;
#pragma unroll
        for (int j = 0; j < 4; ++j) {
            float4 u;
            u.x = acc[r][j * 4 + 0]; u.y = acc[r][j * 4 + 1];
            u.z = acc[r][j * 4 + 2]; u.w = acc[r][j * 4 + 3];
            *(float4*)&base[j * 4] = u;
        }
        lbuf[((long long)grow * 8 + h) * 8 + c] = l[r];
    }
}

// -------- out = combine(partials) @ WcombT^T + bcomb, fused 64x64 --------
__global__ __launch_bounds__(256)
void out_fused(const float* __restrict__ zp, const float* __restrict__ lbuf,
               const float* __restrict__ Bm, const float* __restrict__ bias,
               float* __restrict__ C) {
    const int m0 = blockIdx.x * 64, n0 = blockIdx.y * 64;
    __shared__ float As[64][132];
    __shared__ float Bs[64][68];
    const int t = threadIdx.x;
    const int tx = t & 15, ty = t >> 4;

#pragma unroll
    for (int g = 0; g < 8; ++g) {
        int flat = g * 256 + t;
        int row = flat >> 5;
        int f4c = flat & 31;
        int d0 = f4c * 4, h = d0 >> 4;
        long long grow = m0 + row;
        const float* pb = zp + grow * 1024 + d0;
        float4 s = {0.f, 0.f, 0.f, 0.f};
#pragma unroll
        for (int c = 0; c < 8; ++c) {
            float4 a = *(const float4*)&pb[c * 128];
            s.x += a.x; s.y += a.y; s.z += a.z; s.w += a.w;
        }
        const float* lr = lbuf + (grow * 8 + h) * 8;
        float4 l0 = *(const float4*)&lr[0];
        float4 l1 = *(const float4*)&lr[4];
        float L = (l0.x + l0.y + l0.z + l0.w) + (l1.x + l1.y + l1.z + l1.w);
        float inv = 1.f / L;
        s.x *= inv; s.y *= inv; s.z *= inv; s.w *= inv;
        *(float4*)&As[row][d0] = s;
    }

    float acc[4][4] = {};
    for (int kt = 0; kt < 128; kt += 64) {
        __syncthreads();
#pragma unroll
        for (int r = 0; r < 4; ++r) {
            int flat = r * 256 + t;
            int row = flat >> 4;
            int k0 = (flat & 15) * 4;
            *(float4*)&Bs[row][k0] = *(const float4*)&Bm[(long long)(n0 + row) * 128 + kt + k0];
        }
        __syncthreads();
#pragma unroll
        for (int kc = 0; kc < 16; ++kc) {
            float4 a4[4], b4[4];
#pragma unroll
            for (int i = 0; i < 4; ++i) a4[i] = *(float4*)&As[16 * i + ty][kt + kc * 4];
#pragma unroll
            for (int j = 0; j < 4; ++j) b4[j] = *(float4*)&Bs[16 * j + tx][kc * 4];
#pragma unroll
            for (int i = 0; i < 4; ++i)
#pragma unroll
                for (int j = 0; j < 4; ++j) {
                    float s = acc[i][j];
                    s = fmaf(a4[i].x, b4[j].x, s);
                    s = fmaf(a4[i].y, b4[j].y, s);
                    s = fmaf(a4[i].z, b4[j].z, s);
                    s = fmaf(a4[i].w, b4[j].w, s);
                    acc[i][j] = s;
                }
        }
    }
#pragma unroll
    for (int i = 0; i < 4; ++i) {
        int row = m0 + 16 * i + ty;
#pragma unroll
        for (int j = 0; j < 4; ++j) {
            int col = n0 + 16 * j + tx;
            C[(long long)row * 128 + col] = acc[i][j] + bias[col];
        }
    }
}

extern "C" void kernel_launch(void* const* d_in, const int* in_sizes, int n_in,
                              void* d_out, int out_size, void* d_ws, size_t ws_size,
                              hipStream_t stream) {
    (void)in_sizes; (void)n_in; (void)out_size; (void)ws_size;
    const float* H    = (const float*)d_in[0];
    const float* Aadj = (const float*)d_in[1];
    const float* Wlin = (const float*)d_in[2];
    const float* blin = (const float*)d_in[3];
    const float* Win  = (const float*)d_in[4];
    const float* bin  = (const float*)d_in[5];
    const float* Wout = (const float*)d_in[6];
    const float* bout = (const float*)d_in[7];
    const float* Wfin = (const float*)d_in[8];
    const float* bfin = (const float*)d_in[9];
    float* out = (float*)d_out;
    char* ws = (char*)d_ws;

    u16*   WlinTb = (u16*)(ws + 0);           // 32 KB bf16
    u16*   WinTb  = (u16*)(ws + 32768);       // 96 KB bf16
    float* WcombT = (float*)(ws + 131072);    // 64 KB
    float* bcomb  = (float*)(ws + 196608);    // 512 B
    float* rowsum = (float*)(ws + 197120);    // 32 KB
    u16*   Hb     = (u16*)(ws + 262144);      // 2 MB bf16 (H cast)
    u16*   Hpb    = (u16*)(ws + 2359296);     // 2 MB bf16
    float* qkv    = (float*)(ws + 4653056);   // 10.5 MB mixed (q f32|k f16|v f32)
    float* lbuf   = (float*)(ws + 17235968);  // 2 MB
    float* z      = (float*)(ws + 19333120);  // 32 MB (scores -> partials)

    // prep: Hb cast (1M) + weights (81920) => 4416 blocks
    prep_k<<<4416, 256, 0, stream>>>(H, Wlin, Win, Wout, Wfin, bout, bfin,
                                     Hb, WlinTb, WinTb, WcombT, bcomb, rowsum);
    // Hp = Hb @ WlinTb^T + blin -> bf16  (MFMA)
    mfma_hp<<<64, 256, 0, stream>>>(Hb, WlinTb, blin, Hpb);
    // merged: z-gate (512 blocks) + qkv (192 blocks)
    mfma_qkvz<<<704, 256, 0, stream>>>(Hpb, WinTb, bin, qkv, Aadj, z, rowsum);
    // flash pass 1 (f16 dot2; aw inline; partials into z + lbuf)
    flash_pass1<<<dim3(16, 8, 8), 256, 0, stream>>>(qkv, z, rowsum, lbuf);
    // out = combine(partials) @ Wcomb + bcomb
    out_fused<<<dim3(128, 2), 256, 0, stream>>>(z, lbuf, WcombT, bcomb, out);
}

// Round 16
// 205.882 us; speedup vs baseline: 1.9137x; 1.8943x over previous
//
#include <hip/hip_runtime.h>
#include <hip/hip_bf16.h>

// GraphAttentionLayer: B=8,N=1024,FIN=E=OUT=128,NH=8,HD=16. f32 in/out.
// R16: flash restored to the EXACT R13 kernel (Vs stride 160, h*20, LDS
// 41728B, bounds (256,3)) -- measured 68.6us. R14/R15's Vs stride-144 edit
// flipped codegen into a 56-VGPR low-ILP schedule (258us, VALUBusy 14%,
// no spill traffic): register-count chaos, not launch bounds (R15 proved).
// Keeps R14 non-flash wins: MFMA Hp, merged qkv+z dispatch, Hb bf16 prep.

using u16 = unsigned short;
typedef short bf16x8 __attribute__((ext_vector_type(8)));
typedef float f32x4 __attribute__((ext_vector_type(4)));
typedef _Float16 f16;
typedef _Float16 f16x2 __attribute__((ext_vector_type(2)));

#if defined(__has_builtin)
#if __has_builtin(__builtin_amdgcn_fdot2)
#define HAS_FDOT2 1
#endif
#endif

__device__ __forceinline__ u16 f2b(float f) {
    unsigned u = __float_as_uint(f);
    return (u16)((u + 0x7fffu + ((u >> 16) & 1u)) >> 16);  // RNE
}

// ---- prep: Hb bf16 cast + rowsum zero + WlinTb/WinTb bf16 + Wcomb ----
__global__ void prep_k(const float* __restrict__ H, const float* __restrict__ Wlin,
                       const float* __restrict__ Win,
                       const float* __restrict__ Wout, const float* __restrict__ Wfin,
                       const float* __restrict__ bout, const float* __restrict__ bfin,
                       u16* __restrict__ Hb, u16* __restrict__ WlinTb,
                       u16* __restrict__ WinTb,
                       float* __restrict__ WcombT, float* __restrict__ bcomb,
                       float* __restrict__ rowsum) {
    int i = blockIdx.x * 256 + threadIdx.x;   // 0..1130495
    if (i < 1048576) {
        Hb[i] = f2b(H[i]);
        return;
    }
    int j = i - 1048576;                      // 0..81919
    if (j < 8192) rowsum[j] = 0.f;
    if (j < 16384) {
        WlinTb[(j & 127) * 128 + (j >> 7)] = f2b(Wlin[j]);
    } else if (j < 65536) {
        int k = j - 16384;                    // Win 128x384 -> WinTb 384x128 bf16
        int r = k / 384, c = k - r * 384;
        WinTb[c * 128 + r] = f2b(Win[k]);
    } else {
        int k = j - 65536;
        int o = k & 127, e = k >> 7;          // o fastest: Wfin coalesced
        float s = 0.f;
        for (int kk = 0; kk < 128; ++kk)
            s = fmaf(Wout[e * 128 + kk], Wfin[kk * 128 + o], s);
        WcombT[o * 128 + e] = s;
        if (e == 0) {
            float sb = bfin[o];
            for (int kk = 0; kk < 128; ++kk)
                sb = fmaf(bout[kk], Wfin[kk * 128 + o], sb);
            bcomb[o] = sb;
        }
    }
}

// ------- Hp = Hb @ WlinTb^T + blin : MFMA, 128-row blocks, bf16 out -------
__global__ __launch_bounds__(256)
void mfma_hp(const u16* __restrict__ Ab, const u16* __restrict__ Bb,
             const float* __restrict__ bias, u16* __restrict__ C) {
    const int m0 = blockIdx.x * 128;
    const int t = threadIdx.x;
    const int wave = t >> 6, lane = t & 63;
    const int wm = (wave >> 1) * 64, wn = (wave & 1) * 64;
    const int m16 = lane & 15, kq = lane >> 4;
    f32x4 acc[4][4] = {};

#pragma unroll
    for (int kc = 0; kc < 4; ++kc) {
        bf16x8 af[4], bf[4];
#pragma unroll
        for (int i = 0; i < 4; ++i)
            af[i] = *(const bf16x8*)&Ab[(long long)(m0 + wm + i * 16 + m16) * 128 + kc * 32 + kq * 8];
#pragma unroll
        for (int j = 0; j < 4; ++j)
            bf[j] = *(const bf16x8*)&Bb[(long long)(wn + j * 16 + m16) * 128 + kc * 32 + kq * 8];
#pragma unroll
        for (int i = 0; i < 4; ++i)
#pragma unroll
            for (int j = 0; j < 4; ++j)
                acc[i][j] = __builtin_amdgcn_mfma_f32_16x16x32_bf16(af[i], bf[j], acc[i][j], 0, 0, 0);
    }
#pragma unroll
    for (int i = 0; i < 4; ++i) {
#pragma unroll
        for (int r = 0; r < 4; ++r) {
            long long row = m0 + wm + i * 16 + kq * 4 + r;
#pragma unroll
            for (int j = 0; j < 4; ++j) {
                int col = wn + j * 16 + m16;
                C[row * 128 + col] = f2b(acc[i][j][r] + bias[col]);
            }
        }
    }
}

// ---- merged: blk<512 -> z = lrelu(Hpb@Hpb^T)*A + exp-rowsum;
//      blk>=512 -> qkv = Hpb @ WinTb^T + bin (mixed layout) ----
__global__ __launch_bounds__(256)
void mfma_qkvz(const u16* __restrict__ Hpb, const u16* __restrict__ WinTb,
               const float* __restrict__ bin, float* __restrict__ Cq,
               const float* __restrict__ G, float* __restrict__ Z,
               float* __restrict__ rowsum) {
    const int blk = blockIdx.x;
    const int t = threadIdx.x;
    const int wave = t >> 6, lane = t & 63;
    const int wm = (wave >> 1) * 64, wn = (wave & 1) * 64;
    const int m16 = lane & 15, kq = lane >> 4;
    f32x4 acc[4][4] = {};

    if (blk < 512) {
        const int b = blk >> 6, mt = (blk >> 3) & 7, nt = blk & 7;
        const u16* Ab = Hpb + (long long)b * 1024 * 128;
        const int m0 = mt * 128, n0 = nt * 128;
#pragma unroll
        for (int kc = 0; kc < 4; ++kc) {
            bf16x8 af[4], bf[4];
#pragma unroll
            for (int i = 0; i < 4; ++i)
                af[i] = *(const bf16x8*)&Ab[(long long)(m0 + wm + i * 16 + m16) * 128 + kc * 32 + kq * 8];
#pragma unroll
            for (int j = 0; j < 4; ++j)
                bf[j] = *(const bf16x8*)&Ab[(long long)(n0 + wn + j * 16 + m16) * 128 + kc * 32 + kq * 8];
#pragma unroll
            for (int i = 0; i < 4; ++i)
#pragma unroll
                for (int j = 0; j < 4; ++j)
                    acc[i][j] = __builtin_amdgcn_mfma_f32_16x16x32_bf16(af[i], bf[j], acc[i][j], 0, 0, 0);
        }
        const long long zb = (long long)b * 1024 * 1024;
#pragma unroll
        for (int i = 0; i < 4; ++i) {
#pragma unroll
            for (int r = 0; r < 4; ++r) {
                int row = m0 + wm + i * 16 + kq * 4 + r;
                float es = 0.f;
#pragma unroll
                for (int j = 0; j < 4; ++j) {
                    int col = n0 + wn + j * 16 + m16;
                    float v = acc[i][j][r];
                    v = v >= 0.f ? v : 0.2f * v;                  // LeakyReLU(0.2)
                    v *= G[zb + (long long)row * 1024 + col];     // * adjacency gate
                    Z[zb + (long long)row * 1024 + col] = v;
                    es += __expf(v);                              // m=0: |z| bounded
                }
#pragma unroll
                for (int off = 1; off < 16; off <<= 1) es += __shfl_xor(es, off);
                if (m16 == 0) atomicAdd(&rowsum[b * 1024 + row], es);
            }
        }
    } else {
        const int q = blk - 512;
        const int mt = q & 63, slab = q >> 6;   // 0=q, 1=k, 2=v
        const int m0 = mt * 128;
        const u16* Bslab = WinTb + (long long)slab * 128 * 128;
#pragma unroll
        for (int kc = 0; kc < 4; ++kc) {
            bf16x8 af[4], bf[4];
#pragma unroll
            for (int i = 0; i < 4; ++i)
                af[i] = *(const bf16x8*)&Hpb[(long long)(m0 + wm + i * 16 + m16) * 128 + kc * 32 + kq * 8];
#pragma unroll
            for (int j = 0; j < 4; ++j)
                bf[j] = *(const bf16x8*)&Bslab[(long long)(wn + j * 16 + m16) * 128 + kc * 32 + kq * 8];
#pragma unroll
            for (int i = 0; i < 4; ++i)
#pragma unroll
                for (int j = 0; j < 4; ++j)
                    acc[i][j] = __builtin_amdgcn_mfma_f32_16x16x32_bf16(af[i], bf[j], acc[i][j], 0, 0, 0);
        }
        f16* Ck = (f16*)Cq;
#pragma unroll
        for (int i = 0; i < 4; ++i) {
#pragma unroll
            for (int r = 0; r < 4; ++r) {
                long long row = m0 + wm + i * 16 + kq * 4 + r;
#pragma unroll
                for (int j = 0; j < 4; ++j) {
                    int col = wn + j * 16 + m16;
                    float v = acc[i][j][r] + bin[slab * 128 + col];
                    if (slab == 0)      Cq[row * 320 + col] = v;
                    else if (slab == 1) Ck[row * 640 + 256 + col] = (f16)v;
                    else                Cq[row * 320 + 192 + col] = v;
                }
            }
        }
    }
}

// ---- flash pass 1: EXACT R13 kernel (68.6us measured). f16 K dot2,
// 2 rows/thread, 64-row blocks, grid (16,8,8)=1024, LDS 41728B, 3 blk/CU.
// DO NOT touch Vs stride (160) or bounds: stride 144 flipped codegen to a
// 56-VGPR low-ILP schedule (258us); bounds (256,4) caps VGPR at 64 (spill).
__global__ __launch_bounds__(256, 3)
void flash_pass1(const float* __restrict__ qkv, float* __restrict__ zaw,
                 const float* __restrict__ rowsum, float* __restrict__ lbuf) {
    const int b = blockIdx.y;
    const int n0 = blockIdx.x * 64;
    const int c = blockIdx.z;
    const int t = threadIdx.x;
    const int rg = t >> 3;    // 0..31 slots (2 rows each)
    const int h = t & 7;      // head

    __shared__ u16   Ks[32 * 200];   // f16, head h at col h*24 (banks disjoint)
    __shared__ float Vs[32 * 160];   // f32, head h at col h*20
    __shared__ float AWs[32 * 66];   // transposed [mm][qrow 0..63], stride 66

    const int qr = t >> 2;           // AW staging row (0..63)
    const int mmc = (t & 3) * 8;     // AW staging col group
    const float inv0 = 1.f / rowsum[b * 1024 + n0 + qr];

    f16x2 q2[2][8];
    float acc[2][16];
    float l[2] = {0.f, 0.f};
#pragma unroll
    for (int r = 0; r < 2; ++r) {
        const float* qrow = qkv + (long long)(b * 1024 + n0 + rg * 2 + r) * 320 + h * 16;
#pragma unroll
        for (int j = 0; j < 4; ++j) {
            float4 u = *(const float4*)&qrow[j * 4];
            q2[r][j * 2 + 0] = f16x2{(f16)(u.x * 0.25f), (f16)(u.y * 0.25f)};
            q2[r][j * 2 + 1] = f16x2{(f16)(u.z * 0.25f), (f16)(u.w * 0.25f)};
        }
#pragma unroll
        for (int d = 0; d < 16; ++d) acc[r][d] = 0.f;
    }

    for (int tile = 0; tile < 4; ++tile) {
        const int kbase = c * 128 + tile * 32;
        __syncthreads();
        // stage K (f16) and V (f32): row = t>>3 (0..31), head hh = t&7
        {
            const int row = t >> 3, hh = t & 7;
            const long long grow = b * 1024 + kbase + row;
            const uint4* ksrc = (const uint4*)((const char*)qkv + grow * 1280 + 512 + hh * 32);
            *(uint4*)&Ks[row * 200 + hh * 24] = ksrc[0];
            *(uint4*)&Ks[row * 200 + hh * 24 + 8] = ksrc[1];
            const float* vsrc = qkv + grow * 320 + 192 + hh * 16;
#pragma unroll
            for (int j = 0; j < 4; ++j)
                *(float4*)&Vs[row * 160 + hh * 20 + j * 4] = *(const float4*)&vsrc[j * 4];
        }
        // stage aw tile transposed: AWs[mm][qrow], 64 rows x 32 mm
        {
            const float* zrow = zaw + ((long long)(b * 1024 + n0 + qr)) * 1024 + kbase + mmc;
#pragma unroll
            for (int jj = 0; jj < 2; ++jj) {
                float4 u = *(const float4*)&zrow[jj * 4];
                AWs[(mmc + jj * 4 + 0) * 66 + qr] = __expf(u.x) * inv0;
                AWs[(mmc + jj * 4 + 1) * 66 + qr] = __expf(u.y) * inv0;
                AWs[(mmc + jj * 4 + 2) * 66 + qr] = __expf(u.z) * inv0;
                AWs[(mmc + jj * 4 + 3) * 66 + qr] = __expf(u.w) * inv0;
            }
        }
        __syncthreads();

#pragma unroll 2
        for (int mm = 0; mm < 32; ++mm) {
            const f16x2* kp = (const f16x2*)&Ks[mm * 200 + h * 24];
            f16x2 k2[8];
#pragma unroll
            for (int d = 0; d < 8; ++d) k2[d] = kp[d];
            const float* vp = &Vs[mm * 160 + h * 20];
            float4 v0 = *(const float4*)&vp[0],  v1 = *(const float4*)&vp[4];
            float4 v2 = *(const float4*)&vp[8],  v3 = *(const float4*)&vp[12];
            float2 awv = *(const float2*)&AWs[mm * 66 + rg * 2];
            float aws[2] = {awv.x, awv.y};
#ifndef HAS_FDOT2
            float kf[16];
#pragma unroll
            for (int d = 0; d < 8; ++d) {
                kf[d * 2 + 0] = (float)k2[d].x;
                kf[d * 2 + 1] = (float)k2[d].y;
            }
#endif
#pragma unroll
            for (int r = 0; r < 2; ++r) {
                float s = aws[r];
#ifdef HAS_FDOT2
#pragma unroll
                for (int d = 0; d < 8; ++d)
                    s = __builtin_amdgcn_fdot2(q2[r][d], k2[d], s, false);
#else
#pragma unroll
                for (int d = 0; d < 8; ++d) {
                    s = fmaf((float)q2[r][d].x, kf[d * 2 + 0], s);
                    s = fmaf((float)q2[r][d].y, kf[d * 2 + 1], s);
                }
#endif
                float p = __expf(s);          // s in [-1,2]: safe, m=0
                l[r] += p;
                acc[r][0]  = fmaf(p, v0.x, acc[r][0]);
                acc[r][1]  = fmaf(p, v0.y, acc[r][1]);
                acc[r][2]  = fmaf(p, v0.z, acc[r][2]);
                acc[r][3]  = fmaf(p, v0.w, acc[r][3]);
                acc[r][4]  = fmaf(p, v1.x, acc[r][4]);
                acc[r][5]  = fmaf(p, v1.y, acc[r][5]);
                acc[r][6]  = fmaf(p, v1.z, acc[r][6]);
                acc[r][7]  = fmaf(p, v1.w, acc[r][7]);
                acc[r][8]  = fmaf(p, v2.x, acc[r][8]);
                acc[r][9]  = fmaf(p, v2.y, acc[r][9]);
                acc[r][10] = fmaf(p, v2.z, acc[r][10]);
                acc[r][11] = fmaf(p, v2.w, acc[r][11]);
                acc[r][12] = fmaf(p, v3.x, acc[r][12]);
                acc[r][13] = fmaf(p, v3.y, acc[r][13]);
                acc[r][14] = fmaf(p, v3.z, acc[r][14]);
                acc[r][15] = fmaf(p, v3.w, acc[r][15]);
            }
        }
    }
#pragma unroll
    for (int r = 0; r < 2; ++r) {
        const int grow = b * 1024 + n0 + rg * 2 + r;
        float* base = zaw + (long long)grow * 1024 + c * 128 + h * 16;
#pragma unroll
        for (int j = 0; j < 4; ++j) {
            float4 u;
            u.x = acc[r][j * 4 + 0]; u.y = acc[r][j * 4 + 1];
            u.z = acc[r][j * 4 + 2]; u.w = acc[r][j * 4 + 3];
            *(float4*)&base[j * 4] = u;
        }
        lbuf[((long long)grow * 8 + h) * 8 + c] = l[r];
    }
}

// -------- out = combine(partials) @ WcombT^T + bcomb, fused 64x64 --------
__global__ __launch_bounds__(256)
void out_fused(const float* __restrict__ zp, const float* __restrict__ lbuf,
               const float* __restrict__ Bm, const float* __restrict__ bias,
               float* __restrict__ C) {
    const int m0 = blockIdx.x * 64, n0 = blockIdx.y * 64;
    __shared__ float As[64][132];
    __shared__ float Bs[64][68];
    const int t = threadIdx.x;
    const int tx = t & 15, ty = t >> 4;

#pragma unroll
    for (int g = 0; g < 8; ++g) {
        int flat = g * 256 + t;
        int row = flat >> 5;
        int f4c = flat & 31;
        int d0 = f4c * 4, h = d0 >> 4;
        long long grow = m0 + row;
        const float* pb = zp + grow * 1024 + d0;
        float4 s = {0.f, 0.f, 0.f, 0.f};
#pragma unroll
        for (int c = 0; c < 8; ++c) {
            float4 a = *(const float4*)&pb[c * 128];
            s.x += a.x; s.y += a.y; s.z += a.z; s.w += a.w;
        }
        const float* lr = lbuf + (grow * 8 + h) * 8;
        float4 l0 = *(const float4*)&lr[0];
        float4 l1 = *(const float4*)&lr[4];
        float L = (l0.x + l0.y + l0.z + l0.w) + (l1.x + l1.y + l1.z + l1.w);
        float inv = 1.f / L;
        s.x *= inv; s.y *= inv; s.z *= inv; s.w *= inv;
        *(float4*)&As[row][d0] = s;
    }

    float acc[4][4] = {};
    for (int kt = 0; kt < 128; kt += 64) {
        __syncthreads();
#pragma unroll
        for (int r = 0; r < 4; ++r) {
            int flat = r * 256 + t;
            int row = flat >> 4;
            int k0 = (flat & 15) * 4;
            *(float4*)&Bs[row][k0] = *(const float4*)&Bm[(long long)(n0 + row) * 128 + kt + k0];
        }
        __syncthreads();
#pragma unroll
        for (int kc = 0; kc < 16; ++kc) {
            float4 a4[4], b4[4];
#pragma unroll
            for (int i = 0; i < 4; ++i) a4[i] = *(float4*)&As[16 * i + ty][kt + kc * 4];
#pragma unroll
            for (int j = 0; j < 4; ++j) b4[j] = *(float4*)&Bs[16 * j + tx][kc * 4];
#pragma unroll
            for (int i = 0; i < 4; ++i)
#pragma unroll
                for (int j = 0; j < 4; ++j) {
                    float s = acc[i][j];
                    s = fmaf(a4[i].x, b4[j].x, s);
                    s = fmaf(a4[i].y, b4[j].y, s);
                    s = fmaf(a4[i].z, b4[j].z, s);
                    s = fmaf(a4[i].w, b4[j].w, s);
                    acc[i][j] = s;
                }
        }
    }
#pragma unroll
    for (int i = 0; i < 4; ++i) {
        int row = m0 + 16 * i + ty;
#pragma unroll
        for (int j = 0; j < 4; ++j) {
            int col = n0 + 16 * j + tx;
            C[(long long)row * 128 + col] = acc[i][j] + bias[col];
        }
    }
}

extern "C" void kernel_launch(void* const* d_in, const int* in_sizes, int n_in,
                              void* d_out, int out_size, void* d_ws, size_t ws_size,
                              hipStream_t stream) {
    (void)in_sizes; (void)n_in; (void)out_size; (void)ws_size;
    const float* H    = (const float*)d_in[0];
    const float* Aadj = (const float*)d_in[1];
    const float* Wlin = (const float*)d_in[2];
    const float* blin = (const float*)d_in[3];
    const float* Win  = (const float*)d_in[4];
    const float* bin  = (const float*)d_in[5];
    const float* Wout = (const float*)d_in[6];
    const float* bout = (const float*)d_in[7];
    const float* Wfin = (const float*)d_in[8];
    const float* bfin = (const float*)d_in[9];
    float* out = (float*)d_out;
    char* ws = (char*)d_ws;

    u16*   WlinTb = (u16*)(ws + 0);           // 32 KB bf16
    u16*   WinTb  = (u16*)(ws + 32768);       // 96 KB bf16
    float* WcombT = (float*)(ws + 131072);    // 64 KB
    float* bcomb  = (float*)(ws + 196608);    // 512 B
    float* rowsum = (float*)(ws + 197120);    // 32 KB
    u16*   Hb     = (u16*)(ws + 262144);      // 2 MB bf16 (H cast)
    u16*   Hpb    = (u16*)(ws + 2359296);     // 2 MB bf16
    float* qkv    = (float*)(ws + 4653056);   // 10.5 MB mixed (q f32|k f16|v f32)
    float* lbuf   = (float*)(ws + 17235968);  // 2 MB
    float* z      = (float*)(ws + 19333120);  // 32 MB (scores -> partials)

    // prep: Hb cast (1M) + weights (81920) => 4416 blocks
    prep_k<<<4416, 256, 0, stream>>>(H, Wlin, Win, Wout, Wfin, bout, bfin,
                                     Hb, WlinTb, WinTb, WcombT, bcomb, rowsum);
    // Hp = Hb @ WlinTb^T + blin -> bf16  (MFMA)
    mfma_hp<<<64, 256, 0, stream>>>(Hb, WlinTb, blin, Hpb);
    // merged: z-gate (512 blocks) + qkv (192 blocks)
    mfma_qkvz<<<704, 256, 0, stream>>>(Hpb, WinTb, bin, qkv, Aadj, z, rowsum);
    // flash pass 1 (f16 dot2; aw inline; partials into z + lbuf)
    flash_pass1<<<dim3(16, 8, 8), 256, 0, stream>>>(qkv, z, rowsum, lbuf);
    // out = combine(partials) @ Wcomb + bcomb
    out_fused<<<dim3(128, 2), 256, 0, stream>>>(z, lbuf, WcombT, bcomb, out);
}